// Round 1
// baseline (455.345 us; speedup 1.0000x reference)
//
#include <hip/hip_runtime.h>
#include <hip/hip_bf16.h>
#include <stdint.h>

// Problem constants
#define B_   4
#define S_   2048
#define D_   1024
#define H_   16
#define HD_  64
#define M_   8192           // B_*S_
#define LN_EPS 1e-6f

typedef __attribute__((ext_vector_type(4))) float  f32x4;
typedef __attribute__((ext_vector_type(8))) __bf16 bf16x8;

__device__ __forceinline__ unsigned short f2bf(float f) {
  unsigned int u = __float_as_uint(f);
  u += 0x7FFFu + ((u >> 16) & 1u);   // round-to-nearest-even
  return (unsigned short)(u >> 16);
}

typedef const unsigned int __attribute__((address_space(1)))* gas1_t;
typedef unsigned int __attribute__((address_space(3)))*       las3_t;

// async global->LDS, 16B per lane; LDS dest is wave-uniform base + lane*16
__device__ __forceinline__ void gload_lds16(const void* g, void* l) {
  __builtin_amdgcn_global_load_lds((gas1_t)(uintptr_t)g,
                                   (las3_t)(unsigned int)(uintptr_t)l, 16, 0, 0);
}

// ---------------------------------------------------------------- cast f32->bf16
__global__ void castk(const float* __restrict__ src, unsigned short* __restrict__ dst, int n4) {
  int stride = gridDim.x * blockDim.x;
  for (int i = blockIdx.x * blockDim.x + threadIdx.x; i < n4; i += stride) {
    float4 v = ((const float4*)src)[i];
    ushort4 o;
    o.x = f2bf(v.x); o.y = f2bf(v.y); o.z = f2bf(v.z); o.w = f2bf(v.w);
    ((ushort4*)dst)[i] = o;
  }
}

// ------------------------------------------------- cast + transpose W (K x N) -> Wt (N x K) bf16
__global__ void wcast(const float* __restrict__ W, unsigned short* __restrict__ Wt) {
  __shared__ float tile[32][33];
  int tx = threadIdx.x & 31, ty = threadIdx.x >> 5;   // 32 x 8
  int n0 = blockIdx.x * 32, k0 = blockIdx.y * 32;
  #pragma unroll
  for (int r = ty; r < 32; r += 8)
    tile[r][tx] = W[(size_t)(k0 + r) * D_ + n0 + tx];
  __syncthreads();
  #pragma unroll
  for (int r = ty; r < 32; r += 8)
    Wt[(size_t)(n0 + r) * D_ + k0 + tx] = f2bf(tile[tx][r]);
}

// ------------------------------------------------- GEMM C[MxN] = A[Mx1024] * Bt[Nx1024]^T
// 128x128 tile, BK=32, 4 waves (2x2), 16x16x32 bf16 MFMA.
// LN==1: epilogue adds bias, per-head (64-col) LayerNorm, scale/bias, writes bf16.
// LN==0: epilogue adds bias, writes f32.
template <int LN>
__global__ __launch_bounds__(256, 2) void gemm_bt(
    const unsigned short* __restrict__ A,
    const unsigned short* __restrict__ Bt,
    const float* __restrict__ bias,
    const float* __restrict__ lnsc,
    const float* __restrict__ lnbi,
    void* __restrict__ Cout)
{
  __shared__ __align__(16) unsigned short lA[128 * 32];
  __shared__ __align__(16) unsigned short lB[128 * 32];
  const int tid  = threadIdx.x;
  const int wid  = tid >> 6, lane = tid & 63;
  const int lg   = lane >> 4, li = lane & 15;
  const int m0   = blockIdx.x * 128, n0 = blockIdx.y * 128;
  const int wr   = wid >> 1, wc = wid & 1;

  f32x4 acc[4][4] = {};

  const int srow = wid * 32 + (lane >> 2);  // staging row (+16 for instr 1)
  const int sc8  = (lane & 3) * 8;          // k-offset of this lane's 16B chunk

  for (int kt = 0; kt < 32; ++kt) {
    const int k0 = kt * 32;
    #pragma unroll
    for (int i = 0; i < 2; ++i) {
      gload_lds16(A  + (size_t)(m0 + srow + i * 16) * 1024 + k0 + sc8, &lA[(wid * 2 + i) * 512]);
      gload_lds16(Bt + (size_t)(n0 + srow + i * 16) * 1024 + k0 + sc8, &lB[(wid * 2 + i) * 512]);
    }
    __syncthreads();
    bf16x8 af[4], bfr[4];
    #pragma unroll
    for (int mi = 0; mi < 4; ++mi)
      af[mi] = *(const bf16x8*)&lA[(wr * 64 + mi * 16 + li) * 32 + lg * 8];
    #pragma unroll
    for (int nj = 0; nj < 4; ++nj)
      bfr[nj] = *(const bf16x8*)&lB[(wc * 64 + nj * 16 + li) * 32 + lg * 8];
    #pragma unroll
    for (int mi = 0; mi < 4; ++mi)
      #pragma unroll
      for (int nj = 0; nj < 4; ++nj)
        acc[mi][nj] = __builtin_amdgcn_mfma_f32_16x16x32_bf16(af[mi], bfr[nj], acc[mi][nj], 0, 0, 0);
    __syncthreads();
  }

  const int rowb = m0 + wr * 64;
  const int nb   = n0 + wc * 64;   // multiple of 64 -> exactly one head group per wave
  if (LN) {
    float bia[4], scl[4], lnb[4];
    #pragma unroll
    for (int nj = 0; nj < 4; ++nj) {
      int col = nb + nj * 16 + li;
      bia[nj] = bias[col];
      scl[nj] = lnsc[col & 63];
      lnb[nj] = lnbi[col & 63];
    }
    unsigned short* C = (unsigned short*)Cout;
    #pragma unroll
    for (int mi = 0; mi < 4; ++mi) {
      #pragma unroll
      for (int r = 0; r < 4; ++r) {
        float x[4]; float s1 = 0.f, s2 = 0.f;
        #pragma unroll
        for (int nj = 0; nj < 4; ++nj) {
          x[nj] = acc[mi][nj][r] + bia[nj];
          s1 += x[nj]; s2 += x[nj] * x[nj];
        }
        #pragma unroll
        for (int msk = 1; msk < 16; msk <<= 1) {  // reduce over 16 lanes (same row)
          s1 += __shfl_xor(s1, msk);
          s2 += __shfl_xor(s2, msk);
        }
        float mu  = s1 * (1.f / 64.f);
        float var = fmaxf(s2 * (1.f / 64.f) - mu * mu, 0.f);
        float inv = rsqrtf(var + LN_EPS);
        size_t row = (size_t)(rowb + mi * 16 + lg * 4 + r);
        #pragma unroll
        for (int nj = 0; nj < 4; ++nj) {
          float y = (x[nj] - mu) * inv * scl[nj] + lnb[nj];
          C[row * 1024 + nb + nj * 16 + li] = f2bf(y);
        }
      }
    }
  } else {
    float bia[4];
    #pragma unroll
    for (int nj = 0; nj < 4; ++nj) bia[nj] = bias[nb + nj * 16 + li];
    float* C = (float*)Cout;
    #pragma unroll
    for (int mi = 0; mi < 4; ++mi)
      #pragma unroll
      for (int r = 0; r < 4; ++r) {
        size_t row = (size_t)(rowb + mi * 16 + lg * 4 + r);
        #pragma unroll
        for (int nj = 0; nj < 4; ++nj)
          C[row * 1024 + nb + nj * 16 + li] = acc[mi][nj][r] + bia[nj];
      }
  }
}

// ------------------------------------------------- V [8192][1024] -> VT [64 bh][64 hd][2048 s]
__global__ __launch_bounds__(256) void vtrans(const unsigned short* __restrict__ V,
                                              unsigned short* __restrict__ VT) {
  __shared__ __align__(16) unsigned short t[64][72];  // pad to 144B rows
  int bh = blockIdx.y, b = bh >> 4, h = bh & 15;
  int s0 = blockIdx.x * 64;
  int tid = threadIdx.x;
  #pragma unroll
  for (int it = 0; it < 2; ++it) {
    int cid = it * 256 + tid;
    int r = cid >> 3, c = (cid & 7) * 8;
    int4 v = *(const int4*)(V + (size_t)(b * 2048 + s0 + r) * 1024 + h * 64 + c);
    *(int4*)(&t[r][c]) = v;
  }
  __syncthreads();
  #pragma unroll
  for (int it = 0; it < 2; ++it) {
    int cid = it * 256 + tid;
    int hd = cid >> 3, sc = (cid & 7) * 8;
    alignas(16) unsigned short tmp[8];
    #pragma unroll
    for (int j = 0; j < 8; ++j) tmp[j] = t[sc + j][hd];
    *(int4*)(VT + ((size_t)bh * 64 + hd) * 2048 + s0 + sc) = *(int4*)tmp;
  }
}

// ------------------------------------------------- flash attention
// grid (16 q-tiles, 64 bh), 256 threads (4 waves), each wave owns 32 q-rows.
__global__ __launch_bounds__(256, 2) void attn(
    const unsigned short* __restrict__ Q, const unsigned short* __restrict__ K,
    const unsigned short* __restrict__ VT, unsigned short* __restrict__ AO)
{
  __shared__ __align__(16) unsigned short Ks[128 * 64];   // [key][d], XOR-swizzled 16B chunks
  __shared__ __align__(16) unsigned short Vs[64 * 128];   // [d][key], XOR-swizzled
  __shared__ __align__(16) unsigned short Ps[4][32 * 128]; // per-wave P, swizzled
  const int tid = threadIdx.x, wid = tid >> 6, lane = tid & 63;
  const int lg = lane >> 4, li = lane & 15;
  const int qt = blockIdx.x, bh = blockIdx.y, b = bh >> 4, h = bh & 15;

  // Q fragments straight from global (read once, held in regs)
  bf16x8 qf[2][2];
  const int qrow0 = b * 2048 + qt * 128 + wid * 32;
  #pragma unroll
  for (int mi = 0; mi < 2; ++mi)
    #pragma unroll
    for (int kc = 0; kc < 2; ++kc)
      qf[mi][kc] = *(const bf16x8*)(Q + (size_t)(qrow0 + mi * 16 + li) * 1024 + h * 64 + kc * 32 + lg * 8);

  f32x4 o[2][4] = {};
  float mrun[2][4], lrun[2][4];
  #pragma unroll
  for (int mi = 0; mi < 2; ++mi)
    #pragma unroll
    for (int r = 0; r < 4; ++r) { mrun[mi][r] = -1e30f; lrun[mi][r] = 0.f; }

  unsigned short* Pw = &Ps[wid][0];

  for (int kt = 0; kt < 16; ++kt) {
    // stage K tile [128 keys][64 d] (8 chunks/row, source pre-swizzled: slot c holds chunk c^(r&7))
    #pragma unroll
    for (int i = 0; i < 4; ++i) {
      int cid = (wid * 4 + i) * 64 + lane;
      int r = cid >> 3, c = cid & 7;
      gload_lds16(K + (size_t)(b * 2048 + kt * 128 + r) * 1024 + h * 64 + ((c ^ (r & 7)) << 3),
                  &Ks[(wid * 4 + i) * 512]);
    }
    // stage V tile [64 d][128 keys] (16 chunks/row)
    #pragma unroll
    for (int i = 0; i < 4; ++i) {
      int cid = (wid * 4 + i) * 64 + lane;
      int r = cid >> 4, c = cid & 15;
      gload_lds16(VT + ((size_t)bh * 64 + r) * 2048 + kt * 128 + ((c ^ (r & 7)) << 3),
                  &Vs[(wid * 4 + i) * 512]);
    }
    __syncthreads();

    // QK^T: scores tile 32(q) x 128(key) per wave
    f32x4 sacc[2][8] = {};
    #pragma unroll
    for (int kc = 0; kc < 2; ++kc)
      #pragma unroll
      for (int nj = 0; nj < 8; ++nj) {
        int key = nj * 16 + li;
        int slot = (kc * 4 + lg) ^ (key & 7);
        bf16x8 kb = *(const bf16x8*)&Ks[key * 64 + slot * 8];
        #pragma unroll
        for (int mi = 0; mi < 2; ++mi)
          sacc[mi][nj] = __builtin_amdgcn_mfma_f32_16x16x32_bf16(qf[mi][kc], kb, sacc[mi][nj], 0, 0, 0);
      }

    // online softmax; P -> LDS (bf16, swizzled)
    #pragma unroll
    for (int mi = 0; mi < 2; ++mi) {
      #pragma unroll
      for (int r = 0; r < 4; ++r) {
        float tm = -1e30f;
        #pragma unroll
        for (int nj = 0; nj < 8; ++nj) tm = fmaxf(tm, sacc[mi][nj][r]);
        tm *= 0.125f;
        #pragma unroll
        for (int msk = 1; msk < 16; msk <<= 1) tm = fmaxf(tm, __shfl_xor(tm, msk));
        float mnew  = fmaxf(mrun[mi][r], tm);
        float alpha = __expf(mrun[mi][r] - mnew);
        mrun[mi][r] = mnew;
        lrun[mi][r] *= alpha;
        #pragma unroll
        for (int nj = 0; nj < 4; ++nj) o[mi][nj][r] *= alpha;
        float ls = 0.f;
        int row = mi * 16 + lg * 4 + r;
        #pragma unroll
        for (int nj = 0; nj < 8; ++nj) {
          float p = __expf(sacc[mi][nj][r] * 0.125f - mnew);
          ls += p;
          int col  = nj * 16 + li;
          int slot = (col >> 3) ^ (row & 7);
          Pw[row * 128 + slot * 8 + (col & 7)] = f2bf(p);
        }
        #pragma unroll
        for (int msk = 1; msk < 16; msk <<= 1) ls += __shfl_xor(ls, msk);
        lrun[mi][r] += ls;
      }
    }
    __syncthreads();  // P visible; K/V reads below race-free vs next staging via end barrier

    // PV: o += P(32x128) * V(128x64)
    #pragma unroll
    for (int kc = 0; kc < 4; ++kc) {
      bf16x8 pa[2];
      #pragma unroll
      for (int mi = 0; mi < 2; ++mi) {
        int row = mi * 16 + li;
        int slot = (kc * 4 + lg) ^ (row & 7);
        pa[mi] = *(const bf16x8*)&Pw[row * 128 + slot * 8];
      }
      #pragma unroll
      for (int nj = 0; nj < 4; ++nj) {
        int d = nj * 16 + li;
        int slot = (kc * 4 + lg) ^ (d & 7);
        bf16x8 vb = *(const bf16x8*)&Vs[d * 128 + slot * 8];
        #pragma unroll
        for (int mi = 0; mi < 2; ++mi)
          o[mi][nj] = __builtin_amdgcn_mfma_f32_16x16x32_bf16(pa[mi], vb, o[mi][nj], 0, 0, 0);
      }
    }
    __syncthreads();  // everyone done with Ks/Vs before next tile staging
  }

  #pragma unroll
  for (int mi = 0; mi < 2; ++mi)
    #pragma unroll
    for (int r = 0; r < 4; ++r) {
      float inv = 1.0f / lrun[mi][r];
      size_t rowg = (size_t)(qrow0 + mi * 16 + lg * 4 + r);
      #pragma unroll
      for (int nj = 0; nj < 4; ++nj)
        AO[rowg * 1024 + h * 64 + nj * 16 + li] = f2bf(o[mi][nj][r] * inv);
    }
}

// ----------------------------------------------------------------- launch
extern "C" void kernel_launch(void* const* d_in, const int* in_sizes, int n_in,
                              void* d_out, int out_size, void* d_ws, size_t ws_size,
                              hipStream_t stream) {
  const float* inq  = (const float*)d_in[0];
  const float* inkv = (const float*)d_in[1];
  const float* Wq   = (const float*)d_in[2];
  const float* bq   = (const float*)d_in[3];
  const float* Wk   = (const float*)d_in[4];
  const float* bk   = (const float*)d_in[5];
  const float* Wv   = (const float*)d_in[6];
  const float* bv   = (const float*)d_in[7];
  const float* qs   = (const float*)d_in[8];
  const float* qb   = (const float*)d_in[9];
  const float* ksc  = (const float*)d_in[10];
  const float* kbi  = (const float*)d_in[11];
  const float* vsc  = (const float*)d_in[12];
  const float* vbi  = (const float*)d_in[13];
  const float* Wo   = (const float*)d_in[14];
  const float* bo   = (const float*)d_in[15];
  float* out = (float*)d_out;

  char* ws = (char*)d_ws;
  const size_t MB = 1024 * 1024;
  unsigned short* Xq  = (unsigned short*)(ws + 0);        // 16 MB; later reused as AO
  unsigned short* Xkv = (unsigned short*)(ws + 16 * MB);  // 16 MB; later reused as VT
  unsigned short* Wqt = (unsigned short*)(ws + 32 * MB);
  unsigned short* Wkt = (unsigned short*)(ws + 34 * MB);
  unsigned short* Wvt = (unsigned short*)(ws + 36 * MB);
  unsigned short* Wot = (unsigned short*)(ws + 38 * MB);
  unsigned short* Qb  = (unsigned short*)(ws + 40 * MB);
  unsigned short* Kb  = (unsigned short*)(ws + 56 * MB);
  unsigned short* Vb  = (unsigned short*)(ws + 72 * MB);  // end: 88 MB
  unsigned short* VT  = Xkv;  // dead after QKV GEMMs
  unsigned short* AO  = Xq;   // dead after QKV GEMMs

  castk<<<2048, 256, 0, stream>>>(inq,  Xq,  M_ * D_ / 4);
  castk<<<2048, 256, 0, stream>>>(inkv, Xkv, M_ * D_ / 4);
  wcast<<<dim3(32, 32), 256, 0, stream>>>(Wq, Wqt);
  wcast<<<dim3(32, 32), 256, 0, stream>>>(Wk, Wkt);
  wcast<<<dim3(32, 32), 256, 0, stream>>>(Wv, Wvt);
  wcast<<<dim3(32, 32), 256, 0, stream>>>(Wo, Wot);

  gemm_bt<1><<<dim3(64, 8), 256, 0, stream>>>(Xq,  Wqt, bq, qs,  qb,  (void*)Qb);
  gemm_bt<1><<<dim3(64, 8), 256, 0, stream>>>(Xkv, Wkt, bk, ksc, kbi, (void*)Kb);
  gemm_bt<1><<<dim3(64, 8), 256, 0, stream>>>(Xkv, Wvt, bv, vsc, vbi, (void*)Vb);

  vtrans<<<dim3(32, 64), 256, 0, stream>>>(Vb, VT);
  attn<<<dim3(16, 64), 256, 0, stream>>>(Qb, Kb, VT, AO);

  gemm_bt<0><<<dim3(64, 8), 256, 0, stream>>>(AO, Wot, bo, nullptr, nullptr, (void*)out);
}

// Round 6
// 367.861 us; speedup vs baseline: 1.2378x; 1.2378x over previous
//
#include <hip/hip_runtime.h>
#include <hip/hip_bf16.h>
#include <stdint.h>

// Problem constants
#define B_   4
#define S_   2048
#define D_   1024
#define H_   16
#define HD_  64
#define M_   8192           // B_*S_
#define LN_EPS 1e-6f

typedef __attribute__((ext_vector_type(4)))  float  f32x4;
typedef __attribute__((ext_vector_type(16))) float  f32x16;
typedef __attribute__((ext_vector_type(8)))  __bf16 bf16x8;

__device__ __forceinline__ unsigned short f2bf(float f) {
  unsigned int u = __float_as_uint(f);
  u += 0x7FFFu + ((u >> 16) & 1u);   // round-to-nearest-even
  return (unsigned short)(u >> 16);
}

// v_cvt_pk_bf16_f32: dst = {bf16(a) in low16, bf16(b) in high16}
__device__ __forceinline__ unsigned int cvtpk(float a, float b) {
  unsigned int r;
  asm("v_cvt_pk_bf16_f32 %0, %1, %2" : "=v"(r) : "v"(a), "v"(b));
  return r;
}

// v_exp_f32 computes 2^x
__device__ __forceinline__ float exp2a(float x) {
  float r;
  asm("v_exp_f32 %0, %1" : "=v"(r) : "v"(x));
  return r;
}

typedef const unsigned int __attribute__((address_space(1)))* gas1_t;
typedef unsigned int __attribute__((address_space(3)))*       las3_t;

// async global->LDS, 16B per lane; LDS dest is wave-uniform base + lane*16
__device__ __forceinline__ void gload_lds16(const void* g, void* l) {
  __builtin_amdgcn_global_load_lds((gas1_t)(uintptr_t)g,
                                   (las3_t)(unsigned int)(uintptr_t)l, 16, 0, 0);
}

// ---------------------------------------------------------------- cast f32->bf16
__global__ void castk(const float* __restrict__ src, unsigned short* __restrict__ dst, int n4) {
  int stride = gridDim.x * blockDim.x;
  for (int i = blockIdx.x * blockDim.x + threadIdx.x; i < n4; i += stride) {
    float4 v = ((const float4*)src)[i];
    ushort4 o;
    o.x = f2bf(v.x); o.y = f2bf(v.y); o.z = f2bf(v.z); o.w = f2bf(v.w);
    ((ushort4*)dst)[i] = o;
  }
}

// ------------------------------------------------- cast + transpose W (K x N) -> Wt (N x K) bf16
__global__ void wcast(const float* __restrict__ W, unsigned short* __restrict__ Wt) {
  __shared__ float tile[32][33];
  int tx = threadIdx.x & 31, ty = threadIdx.x >> 5;   // 32 x 8
  int n0 = blockIdx.x * 32, k0 = blockIdx.y * 32;
  #pragma unroll
  for (int r = ty; r < 32; r += 8)
    tile[r][tx] = W[(size_t)(k0 + r) * D_ + n0 + tx];
  __syncthreads();
  #pragma unroll
  for (int r = ty; r < 32; r += 8)
    Wt[(size_t)(n0 + r) * D_ + k0 + tx] = f2bf(tile[tx][r]);
}

// ------------------------------------------------- GEMM C[MxN] = A[Mx1024] * Bt[Nx1024]^T
// 128x128 tile, BK=32, 4 waves (2x2), 16x16x32 bf16 MFMA.
// LN==1: epilogue adds bias, per-head (64-col) LayerNorm, scale/bias*oscale, writes bf16.
// LN==0: epilogue adds bias, writes f32.
template <int LN>
__global__ __launch_bounds__(256, 2) void gemm_bt(
    const unsigned short* __restrict__ A,
    const unsigned short* __restrict__ Bt,
    const float* __restrict__ bias,
    const float* __restrict__ lnsc,
    const float* __restrict__ lnbi,
    float oscale,
    void* __restrict__ Cout)
{
  __shared__ __align__(16) unsigned short lA[128 * 32];
  __shared__ __align__(16) unsigned short lB[128 * 32];
  const int tid  = threadIdx.x;
  const int wid  = tid >> 6, lane = tid & 63;
  const int lg   = lane >> 4, li = lane & 15;
  const int m0   = blockIdx.x * 128, n0 = blockIdx.y * 128;
  const int wr   = wid >> 1, wc = wid & 1;

  f32x4 acc[4][4] = {};

  const int srow = wid * 32 + (lane >> 2);  // staging row (+16 for instr 1)
  const int sc8  = (lane & 3) * 8;          // k-offset of this lane's 16B chunk

  for (int kt = 0; kt < 32; ++kt) {
    const int k0 = kt * 32;
    #pragma unroll
    for (int i = 0; i < 2; ++i) {
      gload_lds16(A  + (size_t)(m0 + srow + i * 16) * 1024 + k0 + sc8, &lA[(wid * 2 + i) * 512]);
      gload_lds16(Bt + (size_t)(n0 + srow + i * 16) * 1024 + k0 + sc8, &lB[(wid * 2 + i) * 512]);
    }
    __syncthreads();
    bf16x8 af[4], bfr[4];
    #pragma unroll
    for (int mi = 0; mi < 4; ++mi)
      af[mi] = *(const bf16x8*)&lA[(wr * 64 + mi * 16 + li) * 32 + lg * 8];
    #pragma unroll
    for (int nj = 0; nj < 4; ++nj)
      bfr[nj] = *(const bf16x8*)&lB[(wc * 64 + nj * 16 + li) * 32 + lg * 8];
    #pragma unroll
    for (int mi = 0; mi < 4; ++mi)
      #pragma unroll
      for (int nj = 0; nj < 4; ++nj)
        acc[mi][nj] = __builtin_amdgcn_mfma_f32_16x16x32_bf16(af[mi], bfr[nj], acc[mi][nj], 0, 0, 0);
    __syncthreads();
  }

  const int rowb = m0 + wr * 64;
  const int nb   = n0 + wc * 64;   // multiple of 64 -> exactly one head group per wave
  if (LN) {
    float bia[4], scl[4], lnb[4];
    #pragma unroll
    for (int nj = 0; nj < 4; ++nj) {
      int col = nb + nj * 16 + li;
      bia[nj] = bias[col];
      scl[nj] = lnsc[col & 63] * oscale;
      lnb[nj] = lnbi[col & 63] * oscale;
    }
    unsigned short* C = (unsigned short*)Cout;
    #pragma unroll
    for (int mi = 0; mi < 4; ++mi) {
      #pragma unroll
      for (int r = 0; r < 4; ++r) {
        float x[4]; float s1 = 0.f, s2 = 0.f;
        #pragma unroll
        for (int nj = 0; nj < 4; ++nj) {
          x[nj] = acc[mi][nj][r] + bia[nj];
          s1 += x[nj]; s2 += x[nj] * x[nj];
        }
        #pragma unroll
        for (int msk = 1; msk < 16; msk <<= 1) {  // reduce over 16 lanes (same row)
          s1 += __shfl_xor(s1, msk);
          s2 += __shfl_xor(s2, msk);
        }
        float mu  = s1 * (1.f / 64.f);
        float var = fmaxf(s2 * (1.f / 64.f) - mu * mu, 0.f);
        float inv = rsqrtf(var + LN_EPS);
        size_t row = (size_t)(rowb + mi * 16 + lg * 4 + r);
        #pragma unroll
        for (int nj = 0; nj < 4; ++nj) {
          float y = (x[nj] - mu) * inv * scl[nj] + lnb[nj];
          C[row * 1024 + nb + nj * 16 + li] = f2bf(y);
        }
      }
    }
  } else {
    float bia[4];
    #pragma unroll
    for (int nj = 0; nj < 4; ++nj) bia[nj] = bias[nb + nj * 16 + li];
    float* C = (float*)Cout;
    #pragma unroll
    for (int mi = 0; mi < 4; ++mi)
      #pragma unroll
      for (int r = 0; r < 4; ++r) {
        size_t row = (size_t)(rowb + mi * 16 + lg * 4 + r);
        #pragma unroll
        for (int nj = 0; nj < 4; ++nj)
          C[row * 1024 + nb + nj * 16 + li] = acc[mi][nj][r] + bia[nj];
      }
  }
}

// ------------------------------------------------- V [8192][1024] -> VT [64 bh][64 hd][2048 s]
__global__ __launch_bounds__(256) void vtrans(const unsigned short* __restrict__ V,
                                              unsigned short* __restrict__ VT) {
  __shared__ __align__(16) unsigned short t[64][72];
  int bh = blockIdx.y, b = bh >> 4, h = bh & 15;
  int s0 = blockIdx.x * 64;
  int tid = threadIdx.x;
  #pragma unroll
  for (int it = 0; it < 2; ++it) {
    int cid = it * 256 + tid;
    int r = cid >> 3, c = (cid & 7) * 8;
    int4 v = *(const int4*)(V + (size_t)(b * 2048 + s0 + r) * 1024 + h * 64 + c);
    *(int4*)(&t[r][c]) = v;
  }
  __syncthreads();
  #pragma unroll
  for (int it = 0; it < 2; ++it) {
    int cid = it * 256 + tid;
    int hd = cid >> 3, sc = (cid & 7) * 8;
    alignas(16) unsigned short tmp[8];
    #pragma unroll
    for (int j = 0; j < 8; ++j) tmp[j] = t[sc + j][hd];
    *(int4*)(VT + ((size_t)bh * 64 + hd) * 2048 + s0 + sc) = *(int4*)tmp;
  }
}

// ------------------------------------------------- flash attention, swapped-operand form
// 1-D grid of 1024 blocks (XCD-swizzled), 256 threads (4 waves), wave owns 32 q-rows.
// S^T = K*Q^T via mfma_32x32x16 (lane holds 16 scores of ONE q); softmax fully in-register;
// P packed to bf16 in-register (cvt_pk + cross-half shfl); O^T = V^T*P^T.
__global__ __launch_bounds__(256, 4) void attn(
    const unsigned short* __restrict__ Q, const unsigned short* __restrict__ K,
    const unsigned short* __restrict__ VT, unsigned short* __restrict__ AO)
{
  __shared__ __align__(16) unsigned short Ks[128 * 64];   // [key][d], XOR-swizzled 16B chunks
  __shared__ __align__(16) unsigned short Vs[64 * 128];   // [d][key], XOR-swizzled
  const int tid = threadIdx.x, wid = tid >> 6, lane = tid & 63;
  const int hi = lane >> 5, lq = lane & 31;

  // XCD-aware swizzle: 1024 blocks, 8 XCDs -> each XCD owns 8 whole bh groups
  const int bid = blockIdx.x;
  const int swz = (bid & 7) * 128 + (bid >> 3);
  const int qt = swz & 15, bh = swz >> 4, b = bh >> 4, h = bh & 15;

  const int qrow0 = b * 2048 + qt * 128 + wid * 32;

  // Q^T B-fragments (Q pre-scaled by log2e/8 in the LN epilogue):
  // qf[c] covers k-rows d = c*16 + hi*8 .. +7, col q = lq
  bf16x8 qf[4];
  #pragma unroll
  for (int c = 0; c < 4; ++c)
    qf[c] = *(const bf16x8*)(Q + (size_t)(qrow0 + lq) * 1024 + h * 64 + c * 16 + hi * 8);

  f32x16 oacc[2] = {};     // O^T, d-blocks of 32; col q = lq
  float m = -3.0e38f, l = 0.f;

  for (int kt = 0; kt < 16; ++kt) {
    // stage K tile [128 keys][64 d]: slot c holds chunk c^(r&7)
    #pragma unroll
    for (int i = 0; i < 4; ++i) {
      int cid = (wid * 4 + i) * 64 + lane;
      int r = cid >> 3, c = cid & 7;
      gload_lds16(K + (size_t)(b * 2048 + kt * 128 + r) * 1024 + h * 64 + ((c ^ (r & 7)) << 3),
                  &Ks[(wid * 4 + i) * 512]);
    }
    // stage V tile [64 d][128 keys]
    #pragma unroll
    for (int i = 0; i < 4; ++i) {
      int cid = (wid * 4 + i) * 64 + lane;
      int r = cid >> 4, c = cid & 15;
      gload_lds16(VT + ((size_t)bh * 64 + r) * 2048 + kt * 128 + ((c ^ (r & 7)) << 3),
                  &Vs[(wid * 4 + i) * 512]);
    }
    __syncthreads();

    #pragma unroll
    for (int kb = 0; kb < 4; ++kb) {
      // S^T[key][q]: 32 keys x 32 q
      f32x16 sacc = {};
      __builtin_amdgcn_s_setprio(1);
      #pragma unroll
      for (int c = 0; c < 4; ++c) {
        int key = kb * 32 + lq;
        int slot = (c * 2 + hi) ^ (key & 7);
        bf16x8 kf = *(const bf16x8*)&Ks[key * 64 + slot * 8];
        sacc = __builtin_amdgcn_mfma_f32_32x32x16_bf16(kf, qf[c], sacc, 0, 0, 0);
      }
      __builtin_amdgcn_s_setprio(0);

      // block max over 32 keys of this q (16 in-lane + cross-half)
      float bmax = sacc[0];
      #pragma unroll
      for (int r = 1; r < 16; ++r) bmax = fmaxf(bmax, sacc[r]);
      bmax = fmaxf(bmax, __shfl_xor(bmax, 32));

      // defer-max: rescale only when max grows by >8 (log2 domain; P <= 256)
      if (bmax > m + 8.f) {
        float alpha = exp2a(m - bmax);
        m = bmax;
        l *= alpha;
        #pragma unroll
        for (int db = 0; db < 2; ++db)
          #pragma unroll
          for (int r = 0; r < 16; ++r) oacc[db][r] *= alpha;
      }

      // P = 2^(s - m), in place; row-sum partial
      float ls = 0.f;
      #pragma unroll
      for (int r = 0; r < 16; ++r) {
        float e = exp2a(sacc[r] - m);
        sacc[r] = e; ls += e;
      }
      l += ls;

      // pack P^T to bf16: W[i] = rows {2i,2i+1} of this half's ownership
      unsigned int W[8], X[8];
      #pragma unroll
      for (int i = 0; i < 8; ++i) W[i] = cvtpk(sacc[2 * i], sacc[2 * i + 1]);
      #pragma unroll
      for (int i = 0; i < 8; ++i) X[i] = (unsigned int)__shfl_xor((int)W[i], 32);

      // PV: O^T += V^T(32d x 16k) * P^T(16k x 32q), 2 k-chunks x 2 d-blocks
      #pragma unroll
      for (int c2 = 0; c2 < 2; ++c2) {
        const int i0 = c2 * 4;
        union { unsigned int u[4]; bf16x8 v; } pf;
        pf.u[0] = hi ? X[i0 + 2] : W[i0];
        pf.u[1] = hi ? X[i0 + 3] : W[i0 + 1];
        pf.u[2] = hi ? W[i0 + 2] : X[i0];
        pf.u[3] = hi ? W[i0 + 3] : X[i0 + 1];
        __builtin_amdgcn_s_setprio(1);
        #pragma unroll
        for (int db = 0; db < 2; ++db) {
          int d = db * 32 + lq;
          int chunk = kb * 4 + c2 * 2 + hi;
          int slot = chunk ^ (d & 7);
          bf16x8 vf = *(const bf16x8*)&Vs[d * 128 + slot * 8];
          oacc[db] = __builtin_amdgcn_mfma_f32_32x32x16_bf16(vf, pf.v, oacc[db], 0, 0, 0);
        }
        __builtin_amdgcn_s_setprio(0);
      }
    }
    __syncthreads();
  }

  // epilogue: combine halves' l, scale, pack, store O (row q = lq, cols d)
  l += __shfl_xor(l, 32);
  float linv = 1.f / l;
  #pragma unroll
  for (int db = 0; db < 2; ++db)
    #pragma unroll
    for (int g = 0; g < 4; ++g) {
      unsigned int w0 = cvtpk(oacc[db][4 * g] * linv,     oacc[db][4 * g + 1] * linv);
      unsigned int w1 = cvtpk(oacc[db][4 * g + 2] * linv, oacc[db][4 * g + 3] * linv);
      uint2 wv; wv.x = w0; wv.y = w1;
      *(uint2*)(AO + (size_t)(qrow0 + lq) * 1024 + h * 64 + db * 32 + g * 8 + hi * 4) = wv;
    }
}

// ----------------------------------------------------------------- launch
extern "C" void kernel_launch(void* const* d_in, const int* in_sizes, int n_in,
                              void* d_out, int out_size, void* d_ws, size_t ws_size,
                              hipStream_t stream) {
  const float* inq  = (const float*)d_in[0];
  const float* inkv = (const float*)d_in[1];
  const float* Wq   = (const float*)d_in[2];
  const float* bq   = (const float*)d_in[3];
  const float* Wk   = (const float*)d_in[4];
  const float* bk   = (const float*)d_in[5];
  const float* Wv   = (const float*)d_in[6];
  const float* bv   = (const float*)d_in[7];
  const float* qs   = (const float*)d_in[8];
  const float* qb   = (const float*)d_in[9];
  const float* ksc  = (const float*)d_in[10];
  const float* kbi  = (const float*)d_in[11];
  const float* vsc  = (const float*)d_in[12];
  const float* vbi  = (const float*)d_in[13];
  const float* Wo   = (const float*)d_in[14];
  const float* bo   = (const float*)d_in[15];
  float* out = (float*)d_out;

  char* ws = (char*)d_ws;
  const size_t MB = 1024 * 1024;
  unsigned short* Xq  = (unsigned short*)(ws + 0);        // 16 MB; later reused as AO
  unsigned short* Xkv = (unsigned short*)(ws + 16 * MB);  // 16 MB; later reused as VT
  unsigned short* Wqt = (unsigned short*)(ws + 32 * MB);
  unsigned short* Wkt = (unsigned short*)(ws + 34 * MB);
  unsigned short* Wvt = (unsigned short*)(ws + 36 * MB);
  unsigned short* Wot = (unsigned short*)(ws + 38 * MB);
  unsigned short* Qb  = (unsigned short*)(ws + 40 * MB);
  unsigned short* Kb  = (unsigned short*)(ws + 56 * MB);
  unsigned short* Vb  = (unsigned short*)(ws + 72 * MB);  // end: 88 MB
  unsigned short* VT  = Xkv;  // dead after QKV GEMMs
  unsigned short* AO  = Xq;   // dead after QKV GEMMs

  const float K2 = 0.18033688011112042f;  // log2(e)/8: folds softmax scale + exp2 base into Q

  castk<<<2048, 256, 0, stream>>>(inq,  Xq,  M_ * D_ / 4);
  castk<<<2048, 256, 0, stream>>>(inkv, Xkv, M_ * D_ / 4);
  wcast<<<dim3(32, 32), 256, 0, stream>>>(Wq, Wqt);
  wcast<<<dim3(32, 32), 256, 0, stream>>>(Wk, Wkt);
  wcast<<<dim3(32, 32), 256, 0, stream>>>(Wv, Wvt);
  wcast<<<dim3(32, 32), 256, 0, stream>>>(Wo, Wot);

  gemm_bt<1><<<dim3(64, 8), 256, 0, stream>>>(Xq,  Wqt, bq, qs,  qb,  K2,  (void*)Qb);
  gemm_bt<1><<<dim3(64, 8), 256, 0, stream>>>(Xkv, Wkt, bk, ksc, kbi, 1.0f, (void*)Kb);
  gemm_bt<1><<<dim3(64, 8), 256, 0, stream>>>(Xkv, Wvt, bv, vsc, vbi, 1.0f, (void*)Vb);

  vtrans<<<dim3(32, 64), 256, 0, stream>>>(Vb, VT);
  attn<<<1024, 256, 0, stream>>>(Qb, Kb, VT, AO);

  gemm_bt<0><<<dim3(64, 8), 256, 0, stream>>>(AO, Wot, bo, nullptr, nullptr, 1.0f, (void*)out);
}